// Round 15
// baseline (376.668 us; speedup 1.0000x reference)
//
#include <hip/hip_runtime.h>
#include <hip/hip_bf16.h>
#include <hip/hip_cooperative_groups.h>

namespace cg = cooperative_groups;

typedef __attribute__((ext_vector_type(8))) short short8;
typedef __attribute__((ext_vector_type(4))) float floatx4;
typedef __attribute__((ext_vector_type(4))) unsigned short ushort4v;

#define DEVI __device__ __forceinline__

// ---------------- constants ----------------
// B=4, N=512, C_IN=256, RES=7, SR=2, FC_DIM=1024, OUT_CH=94
// M = B*N = 2048 rows, K1 = 256*7*7 = 12544

DEVI unsigned short f2bf(float v) {
  union { __hip_bfloat16 h; unsigned short u; } cv;
  cv.h = __float2bfloat16(v);
  return cv.u;
}
DEVI short f2bfs(float v) { return (short)f2bf(v); }

DEVI void gload16(const void* gptr, void* lptr) {
  __builtin_amdgcn_global_load_lds(
      (const __attribute__((address_space(1))) unsigned int*)gptr,
      (__attribute__((address_space(3))) unsigned int*)(unsigned long long)(uintptr_t)lptr,
      16, 0, 0);
}

// ---------------- fused prep + ROI align ----------------
#define ROI_BLKS   16384
#define CVT1_END   28928
#define CVT2_END   29952
#define GRID_TOTAL 30336

__global__ __launch_bounds__(256) void prep_roi_kernel(
    const float* __restrict__ p3, const float* __restrict__ p4,
    const float* __restrict__ p5, const float* __restrict__ bbox,
    const int* __restrict__ aid, unsigned short* __restrict__ X,
    const float* __restrict__ fc1_w, unsigned short* __restrict__ W1b,
    const float* __restrict__ fc2_w, unsigned short* __restrict__ W2b,
    const float* __restrict__ pred_w, unsigned short* __restrict__ W3b) {
  constexpr int PS = 260;   // slow: f32 per-channel stride
  constexpr int PBS = 280;  // slow: bf16 per-channel stride (560 B)
  constexpr int PS8 = 260;  // fast: f32 per-GROUP(4ch) stride
  constexpr int PBS8 = 72;  // fast: bf16 per-channel stride (144 B)
  __shared__ float Pf[32 * PS];            // 33280 B; Pb overlays it
  __shared__ float wyx[238];               // wy [7][17] @0, wx [7][17] @119
  __shared__ int sy0[14], sx0[14];
  __shared__ float sly[14], slx[14];

  const int bid = blockIdx.x;
  const int tid = threadIdx.x;

  if (bid >= ROI_BLKS) {
    if (bid < CVT1_END) {
      size_t i = (size_t)(bid - ROI_BLKS) * 256 + tid;
      float4 v = ((const float4*)fc1_w)[i];
      ushort4v o;
      o[0] = f2bf(v.x); o[1] = f2bf(v.y); o[2] = f2bf(v.z); o[3] = f2bf(v.w);
      ((ushort4v*)W1b)[i] = o;
    } else if (bid < CVT2_END) {
      size_t i = (size_t)(bid - CVT1_END) * 256 + tid;
      float4 v = ((const float4*)fc2_w)[i];
      ushort4v o;
      o[0] = f2bf(v.x); o[1] = f2bf(v.y); o[2] = f2bf(v.z); o[3] = f2bf(v.w);
      ((ushort4v*)W2b)[i] = o;
    } else {
      int i = (bid - CVT2_END) * 256 + tid;
      int row = i >> 10;
      W3b[i] = (row < 94) ? f2bf(pred_w[i]) : (unsigned short)0;
    }
    return;
  }

  // ---------------- ROI branch ----------------
  unsigned short* Pb = (unsigned short*)Pf;
  const int box = bid & 2047;
  const int oct = bid >> 11;               // channels oct*32 ..
  const int b = box >> 9;
  const int lane = tid & 63, wid = tid >> 6;

  const int lvl = aid[box] / 3;
  const int H = 64 >> lvl;
  const int HH = H * H;
  const float* base = (lvl == 0) ? p3 : ((lvl == 1) ? p4 : p5);
  const float scale = 0.125f / (float)(1 << lvl);

  // ---- phase A: sample grid ----
  if (tid < 28) {
    int s = tid;
    bool isY = s < 14;
    int k = isY ? s : s - 14;
    float lo = bbox[box * 4 + (isY ? 0 : 1)];
    float hi = bbox[box * 4 + (isY ? 2 : 3)];
    float t = lo * scale - 0.5f;
    float cell = (hi - lo) * scale * (1.0f / 7.0f);
    float pos = t + ((float)k + 0.5f) * 0.5f * cell;   // S=14 samples, SR=2
    pos = fminf(fmaxf(pos, 0.0f), (float)(H - 1));
    int i0 = (int)floorf(pos);
    if (i0 > H - 2) i0 = H - 2;        // fr=1 reproduces the clamp
    float fr = pos - (float)i0;
    if (isY) { sy0[k] = i0; sly[k] = fr; }
    else     { sx0[k] = i0; slx[k] = fr; }
  }
  __syncthreads();

  // fast path iff the whole sample footprint (incl. +1 taps) fits an 8x8 patch
  const int ry8 = min(sy0[0], H - 8), rx8 = min(sx0[0], H - 8);
  const bool fast = (sy0[13] - ry8 <= 6) && (sx0[13] - rx8 <= 6);
  const int ryb = fast ? ry8 : min(sy0[0], H - 16);
  const int rxb = fast ? rx8 : min(sx0[0], H - 16);
  const float* fb = base + ((size_t)b * 256 + oct * 32) * HH + ryb * H + rxb;

  // ---- phase B1: separable pooled weights wy[7][16], wx[7][16] (stride 17) ----
  if (tid < 224) {
    int j = tid;
    bool isY = j < 112;
    int k2 = isY ? j : j - 112;
    int py = k2 >> 4, r = k2 & 15;
    int o0 = isY ? ryb : rxb;
    float acc = 0.f;
#pragma unroll
    for (int ss = 0; ss < 2; ++ss) {
      int s = 2 * py + ss;
      int rel = (isY ? sy0[s] : sx0[s]) - o0;
      float fr = isY ? sly[s] : slx[s];
      if (r == rel)     acc += 1.0f - fr;
      if (r == rel + 1) acc += fr;
    }
    wyx[(isY ? 0 : 119) + py * 17 + r] = acc * 0.5f;
  }

  const int fr = lane & 15, fg = lane >> 4;
  const int cell = wid * 16 + fr;          // 0..63; valid < 49
  const int py = (cell * 37) >> 8;         // cell/7 for 0..63 (py<=9: garbage, masked)
  const int px = cell - py * 7;

  floatx4 acc0 = (floatx4){0.f, 0.f, 0.f, 0.f};   // channels 0..15
  floatx4 acc1 = (floatx4){0.f, 0.f, 0.f, 0.f};   // channels 16..31

  if (fast) {
    // ---- FAST: 8x8 patch, K=64 ----
    {
      const int r8 = (lane & 15) >> 1, c8 = (lane & 1) * 4, lch = lane >> 4;
      const float* s8 = fb + r8 * H + c8;
#pragma unroll
      for (int it = 0; it < 2; ++it) {
        int grp = it * 4 + wid;
        gload16(s8 + (size_t)(grp * 4 + lch) * HH, &Pf[grp * PS8] + lane * 4);
      }
    }
    __syncthreads();

    {
      const int cch = tid & 31, hf = tid >> 5;
      const float* src = &Pf[(cch >> 2) * PS8 + (cch & 3) * 64 + hf * 8];
      floatx4 v0 = *(const floatx4*)src, v1 = *(const floatx4*)(src + 4);
      __syncthreads();
      unsigned int d0 = (unsigned int)f2bf(v0[0]) | ((unsigned int)f2bf(v0[1]) << 16);
      unsigned int d1 = (unsigned int)f2bf(v0[2]) | ((unsigned int)f2bf(v0[3]) << 16);
      unsigned int d2 = (unsigned int)f2bf(v1[0]) | ((unsigned int)f2bf(v1[1]) << 16);
      unsigned int d3 = (unsigned int)f2bf(v1[2]) | ((unsigned int)f2bf(v1[3]) << 16);
      *(uint4*)&Pb[cch * PBS8 + hf * 8] = make_uint4(d0, d1, d2, d3);
    }

    float xv[8];
    const float* xp = &wyx[119 + px * 17];
#pragma unroll
    for (int e = 0; e < 8; ++e) xv[e] = xp[e];
    const float w0 = wyx[py * 17 + fg];
    const float w1 = wyx[py * 17 + 4 + fg];
    __syncthreads();

#pragma unroll
    for (int kk = 0; kk < 2; ++kk) {
      short8 af0 = *(const short8*)&Pb[fr * PBS8 + kk * 32 + fg * 8];
      short8 af1 = *(const short8*)&Pb[(16 + fr) * PBS8 + kk * 32 + fg * 8];
      short8 bfr;
      const float w = kk ? w1 : w0;
#pragma unroll
      for (int e = 0; e < 8; ++e) bfr[e] = f2bfs(w * xv[e]);
      acc0 = __builtin_amdgcn_mfma_f32_16x16x32_bf16(af0, bfr, acc0, 0, 0, 0);
      acc1 = __builtin_amdgcn_mfma_f32_16x16x32_bf16(af1, bfr, acc1, 0, 0, 0);
    }
  } else {
    // ---- SLOW: 16x16 patch, K=256 ----
    {
      const int r = lane >> 2, c4 = (lane & 3) * 4;
      const float* src0 = fb + r * H + c4;
#pragma unroll
      for (int it = 0; it < 8; ++it) {
        int ch = it * 4 + wid;
        gload16(src0 + (size_t)ch * HH, &Pf[ch * PS] + lane * 4);
      }
    }
    __syncthreads();

    {
      const int cch = tid & 31, rp = tid >> 5;
      const float* src = &Pf[cch * PS + rp * 32];
      floatx4 v[8];
#pragma unroll
      for (int m = 0; m < 8; ++m) v[m] = *(const floatx4*)(src + 4 * m);
      __syncthreads();
      unsigned int d[16];
#pragma unroll
      for (int m = 0; m < 8; ++m) {
        d[2 * m]     = (unsigned int)f2bf(v[m][0]) | ((unsigned int)f2bf(v[m][1]) << 16);
        d[2 * m + 1] = (unsigned int)f2bf(v[m][2]) | ((unsigned int)f2bf(v[m][3]) << 16);
      }
      unsigned short* dst = &Pb[cch * PBS + rp * 32];
#pragma unroll
      for (int m = 0; m < 4; ++m)
        *(uint4*)(dst + m * 8) = make_uint4(d[4 * m], d[4 * m + 1], d[4 * m + 2], d[4 * m + 3]);
    }

    float xv[8], wyv[8];
    {
      const float* xp = &wyx[119 + px * 17 + (fg & 1) * 8];
#pragma unroll
      for (int e = 0; e < 8; ++e) xv[e] = xp[e];
      const float* wp = &wyx[py * 17 + (fg >> 1)];
#pragma unroll
      for (int kk = 0; kk < 8; ++kk) wyv[kk] = wp[2 * kk];
    }
    __syncthreads();

#pragma unroll
    for (int kk = 0; kk < 8; ++kk) {
      short8 af0 = *(const short8*)&Pb[fr * PBS + kk * 32 + fg * 8];
      short8 af1 = *(const short8*)&Pb[(16 + fr) * PBS + kk * 32 + fg * 8];
      short8 bfr;
      const float w = wyv[kk];
#pragma unroll
      for (int e = 0; e < 8; ++e) bfr[e] = f2bfs(w * xv[e]);
      acc0 = __builtin_amdgcn_mfma_f32_16x16x32_bf16(af0, bfr, acc0, 0, 0, 0);
      acc1 = __builtin_amdgcn_mfma_f32_16x16x32_bf16(af1, bfr, acc1, 0, 0, 0);
    }
  }

  if (cell < 49) {
    unsigned short* xb = X + (size_t)box * 12544 + (size_t)(oct * 32) * 49 + cell;
#pragma unroll
    for (int q = 0; q < 4; ++q) {
      xb[(fg * 4 + q) * 49] = f2bf(acc0[q]);
      xb[(16 + fg * 4 + q) * 49] = f2bf(acc1[q]);
    }
  }
}

// ---------------- GEMM: 128x128 tile, BK=64, T2 XOR-swizzle, split-K, T1 XCD swizzle ----------------
template <int KSPLIT>
__global__ __launch_bounds__(256) void gemm_bt_swz(
    const unsigned short* __restrict__ A, const unsigned short* __restrict__ Bw,
    float* __restrict__ C, int M, int N, int K) {
  constexpr int BM = 128, BN = 128, BK = 64;
  __shared__ unsigned short As[BM * BK];   // 16 KB
  __shared__ unsigned short Bs[BN * BK];   // 16 KB

  const int tid = threadIdx.x;
  const int lane = tid & 63, wid = tid >> 6;
  const int wr = wid >> 1, wc = wid & 1;    // 2x2 waves, 64x64 each
  const int fr = lane & 15, fg = lane >> 4;

  // T1: XCD-aware block swizzle (bijective since nwg % 8 == 0)
  int bx = blockIdx.x, by = blockIdx.y, bz = blockIdx.z;
  {
    const int gx = gridDim.x, gy = gridDim.y;
    const int nwg = gx * gy * gridDim.z;
    if ((nwg & 7) == 0) {
      int lin = bx + gx * (by + gy * bz);
      int swz = (lin & 7) * (nwg >> 3) + (lin >> 3);
      bx = swz % gx;
      int t = swz / gx;
      by = t % gy;
      bz = t / gy;
    }
  }
  const int tm = bx * BM, tn = by * BN;

  const int kLen = K / KSPLIT;
  const int kTiles = kLen / BK;
  const int kBeg = bz * kLen;
  float* Cz = C + (size_t)bz * M * N;

  floatx4 acc[4][4];
#pragma unroll
  for (int i = 0; i < 4; ++i)
#pragma unroll
    for (int j = 0; j < 4; ++j)
      acc[i][j] = (floatx4){0.f, 0.f, 0.f, 0.f};

  for (int t = 0; t < kTiles; ++t) {
    const int k0 = kBeg + t * BK;
#pragma unroll
    for (int s = tid; s < BM * 8; s += 256) {
      int row = s >> 3, sl = s & 7;
      int slg = sl ^ (row & 7);
      gload16(&A[(size_t)(tm + row) * K + k0 + slg * 8], &As[s * 8]);
    }
#pragma unroll
    for (int s = tid; s < BN * 8; s += 256) {
      int row = s >> 3, sl = s & 7;
      int slg = sl ^ (row & 7);
      gload16(&Bw[(size_t)(tn + row) * K + k0 + slg * 8], &Bs[s * 8]);
    }
    __syncthreads();

#pragma unroll
    for (int kk = 0; kk < 2; ++kk) {
      short8 af[4], bf[4];
#pragma unroll
      for (int i = 0; i < 4; ++i) {
        int row = wr * 64 + i * 16 + fr;
        int sl = (kk * 4 + fg) ^ (row & 7);
        af[i] = *reinterpret_cast<const short8*>(&As[(row * 8 + sl) * 8]);
      }
#pragma unroll
      for (int j = 0; j < 4; ++j) {
        int row = wc * 64 + j * 16 + fr;
        int sl = (kk * 4 + fg) ^ (row & 7);
        bf[j] = *reinterpret_cast<const short8*>(&Bs[(row * 8 + sl) * 8]);
      }
#pragma unroll
      for (int i = 0; i < 4; ++i)
#pragma unroll
        for (int j = 0; j < 4; ++j)
          acc[i][j] = __builtin_amdgcn_mfma_f32_16x16x32_bf16(af[i], bf[j], acc[i][j], 0, 0, 0);
    }
    __syncthreads();
  }

#pragma unroll
  for (int i = 0; i < 4; ++i)
#pragma unroll
    for (int j = 0; j < 4; ++j)
#pragma unroll
      for (int q = 0; q < 4; ++q) {
        int rr = tm + wr * 64 + i * 16 + fg * 4 + q;
        int cc = tn + wc * 64 + j * 16 + fr;
        Cz[(size_t)rr * N + cc] = acc[i][j][q];
      }
}

// ---------------- old GEMM (pred head only) ----------------
template <int BM, int BN, int WAVES_M, int WAVES_N, int KSPLIT>
__global__ __launch_bounds__(256) void gemm_bt_kernel(
    const unsigned short* __restrict__ A, const unsigned short* __restrict__ Bw,
    float* __restrict__ C, int M, int N, int K) {
  constexpr int BK = 32;
  constexpr int WM = BM / WAVES_M, WN = BN / WAVES_N;
  constexpr int AF = WM / 16, BF = WN / 16;
  constexpr int ASLOT = BM * 4;
  constexpr int BSLOT = BN * 4;
  __shared__ unsigned short As[BM * BK];
  __shared__ unsigned short Bs[BN * BK];

  const int tid = threadIdx.x;
  const int lane = tid & 63, wid = tid >> 6;
  const int wr = wid / WAVES_N, wc = wid % WAVES_N;
  const int tm = blockIdx.x * BM, tn = blockIdx.y * BN;
  const int fr = lane & 15, fg = lane >> 4;

  const int kLen = K / KSPLIT;
  const int kBeg = blockIdx.z * kLen;
  float* Cz = C + (size_t)blockIdx.z * M * N;

  floatx4 acc[AF][BF];
#pragma unroll
  for (int i = 0; i < AF; ++i)
#pragma unroll
    for (int j = 0; j < BF; ++j)
      acc[i][j] = (floatx4){0.f, 0.f, 0.f, 0.f};

  for (int k0 = kBeg; k0 < kBeg + kLen; k0 += BK) {
#pragma unroll
    for (int s = tid; s < ASLOT; s += 256) {
      int row = s >> 2, kb = (s & 3) << 3;
      gload16(&A[(size_t)(tm + row) * K + k0 + kb], &As[s * 8]);
    }
#pragma unroll
    for (int s = tid; s < BSLOT; s += 256) {
      int row = s >> 2, kb = (s & 3) << 3;
      gload16(&Bw[(size_t)(tn + row) * K + k0 + kb], &Bs[s * 8]);
    }
    __syncthreads();

    short8 af[AF], bfv[BF];
#pragma unroll
    for (int i = 0; i < AF; ++i)
      af[i] = *reinterpret_cast<const short8*>(&As[(wr * WM + i * 16 + fr) * BK + fg * 8]);
#pragma unroll
    for (int j = 0; j < BF; ++j)
      bfv[j] = *reinterpret_cast<const short8*>(&Bs[(wc * WN + j * 16 + fr) * BK + fg * 8]);
#pragma unroll
    for (int i = 0; i < AF; ++i)
#pragma unroll
      for (int j = 0; j < BF; ++j)
        acc[i][j] = __builtin_amdgcn_mfma_f32_16x16x32_bf16(af[i], bfv[j], acc[i][j], 0, 0, 0);
    __syncthreads();
  }

#pragma unroll
  for (int i = 0; i < AF; ++i)
#pragma unroll
    for (int j = 0; j < BF; ++j)
#pragma unroll
      for (int q = 0; q < 4; ++q) {
        int rr = tm + wr * WM + i * 16 + fg * 4 + q;
        int cc = tn + wc * WN + j * 16 + fr;
        Cz[(size_t)rr * N + cc] = acc[i][j][q];
      }
}

// ---------------- fused BatchNorm (cooperative, one launch per BN) ----------------
// 512 blocks x 256 threads (2 blocks/CU -> co-resident). Block = (rowgroup rg =
// blk>>2 of 16 rows, colgroup cgi = blk&3 of 256 cols).
// Phase 1: reduce split-K partials into an LDS tile + per-column sums -> ps/pq.
// grid sync. Phase 2: per-column scale/shift from the 128 partials. Phase 3:
// apply+ReLU+bf16 from the LDS tile (Y never round-trips through HBM).
__global__ __launch_bounds__(256) void bn_fused_kernel(
    const float* __restrict__ Yp, const float* __restrict__ g,
    const float* __restrict__ bta, unsigned short* __restrict__ X,
    int P, size_t pstride, float* __restrict__ ps, float* __restrict__ pq,
    float invM) {
  constexpr int FC = 1024, TS = 264;
  __shared__ float tile[16 * TS];          // 16896 B
  __shared__ float sc[256], sh[256];

  const int blk = blockIdx.x;              // 0..511
  const int tid = threadIdx.x;
  const int rg = blk >> 2, cgi = blk & 3;
  const int c = cgi * 256 + tid;

  // phase 1
  {
    float s = 0.f, ss = 0.f;
    for (int r = 0; r < 16; ++r) {
      size_t idx = (size_t)(rg * 16 + r) * FC + c;
      float v = Yp[idx];
      for (int p = 1; p < P; ++p) v += Yp[idx + (size_t)p * pstride];
      tile[r * TS + tid] = v;
      s += v;
      ss += v * v;
    }
    ps[(size_t)rg * FC + c] = s;
    pq[(size_t)rg * FC + c] = ss;
  }
  cg::this_grid().sync();

  // phase 2: scale/shift for this block's 256 columns
  {
    float s = 0.f, ss = 0.f;
    for (int p = 0; p < 128; ++p) {
      s += ps[(size_t)p * FC + c];
      ss += pq[(size_t)p * FC + c];
    }
    float mean = s * invM;
    float var = ss * invM - mean * mean;
    float rstd = rsqrtf(var + 1e-5f);
    float scv = rstd * g[c];
    sc[tid] = scv;
    sh[tid] = bta[c] - mean * scv;
  }
  __syncthreads();

  // phase 3: apply from LDS tile. thread -> row rg*16+(tid>>4), 16 cols (tid&15)*16
  {
    const int lr = tid >> 4, lc0 = (tid & 15) * 16;
    unsigned short* xo = X + (size_t)(rg * 16 + lr) * FC + cgi * 256 + lc0;
#pragma unroll
    for (int m = 0; m < 4; ++m) {
      int lc = lc0 + m * 4;
      float4 v = *(const float4*)&tile[lr * TS + lc];
      ushort4v o;
      o[0] = f2bf(fmaxf(v.x * sc[lc + 0] + sh[lc + 0], 0.0f));
      o[1] = f2bf(fmaxf(v.y * sc[lc + 1] + sh[lc + 1], 0.0f));
      o[2] = f2bf(fmaxf(v.z * sc[lc + 2] + sh[lc + 2], 0.0f));
      o[3] = f2bf(fmaxf(v.w * sc[lc + 3] + sh[lc + 3], 0.0f));
      *(ushort4v*)(xo + m * 4) = o;
    }
  }
}

// ---------------- decode ----------------
__global__ void decode_kernel(const float* __restrict__ Y3, const float* __restrict__ pb,
                              const float* __restrict__ anchors, const int* __restrict__ aid,
                              float* __restrict__ out) {
  int i = blockIdx.x * blockDim.x + threadIdx.x;
  if (i >= 2048 * 94) return;
  int bn = i / 94;
  int ch = i - bn * 94;
  size_t idx = (size_t)bn * 96 + ch;
  float v = Y3[idx] + Y3[idx + 2048 * 96] + Y3[idx + 2 * 2048 * 96] + Y3[idx + 3 * 2048 * 96];
  v += pb[ch];
  float o = v;
  if (ch >= 4 && ch < 22) {
    int q = ch - 4;
    int d = q % 6;   // within-class: 0,1=yx 2,3=lw 4,5=zh
    if (d < 2) {
      float stride_px = (float)(8 << (aid[bn] / 3));
      o = anchors[(size_t)bn * 4 + d] + v * stride_px;
    } else if (d < 4) {
      float cl = fminf(fmaxf(v, -4.0f), 4.0f);
      o = anchors[(size_t)bn * 4 + d] * expf(cl);
    }
  }
  out[i] = o;
}

// ---------------- launch ----------------
extern "C" void kernel_launch(void* const* d_in, const int* in_sizes, int n_in,
                              void* d_out, int out_size, void* d_ws, size_t ws_size,
                              hipStream_t stream) {
  const float* feat_p3   = (const float*)d_in[0];
  const float* feat_p4   = (const float*)d_in[1];
  const float* feat_p5   = (const float*)d_in[2];
  const float* bbox2d    = (const float*)d_in[3];
  const float* anchors   = (const float*)d_in[4];
  const int*   anchor_id = (const int*)d_in[5];
  const float* fc1_w     = (const float*)d_in[6];
  // d_in[7] fc1_b: cancels through train-mode BN (mean subtraction) — unused
  const float* bn1_g     = (const float*)d_in[8];
  const float* bn1_b     = (const float*)d_in[9];
  const float* fc2_w     = (const float*)d_in[10];
  // d_in[11] fc2_b: cancels — unused
  const float* bn2_g     = (const float*)d_in[12];
  const float* bn2_b     = (const float*)d_in[13];
  const float* pred_w    = (const float*)d_in[14];
  const float* pred_b    = (const float*)d_in[15];
  float* out = (float*)d_out;

  const int M = 2048;          // B*N
  const int K1 = 12544;        // 256*7*7
  const int FC = 1024;
  const int RG = 128;          // BN stats row-groups

  char* ws = (char*)d_ws;
  auto alloc = [&](size_t bytes) -> char* {
    char* p = ws;
    ws += (bytes + 255) & ~(size_t)255;
    return p;
  };
  unsigned short* W1b  = (unsigned short*)alloc((size_t)FC * K1 * 2);
  unsigned short* W2b  = (unsigned short*)alloc((size_t)FC * FC * 2);
  unsigned short* W3b  = (unsigned short*)alloc((size_t)96 * FC * 2);
  unsigned short* X1   = (unsigned short*)alloc((size_t)M * K1 * 2);
  float*          Yp   = (float*)alloc((size_t)7 * M * FC * 4);  // split-K partials (fc1: 7, fc2: 4)
  unsigned short* X2   = (unsigned short*)alloc((size_t)M * FC * 2);
  unsigned short* X3   = (unsigned short*)alloc((size_t)M * FC * 2);
  float*          Y3   = (float*)alloc((size_t)4 * M * 96 * 4);
  float*          ps   = (float*)alloc((size_t)RG * FC * 4);
  float*          pq   = (float*)alloc((size_t)RG * FC * 4);

  // fused: weight conversions (overlapped) + ROI align -> X1
  prep_roi_kernel<<<GRID_TOTAL, 256, 0, stream>>>(
      feat_p3, feat_p4, feat_p5, bbox2d, anchor_id, X1,
      fc1_w, W1b, fc2_w, W2b, pred_w, W3b);

  // fc1: X1 (2048x12544) @ W1^T -> Yp (7 partials; 12544 = 64*196, 196%7==0)
  gemm_bt_swz<7><<<dim3(M / 128, FC / 128, 7), 256, 0, stream>>>(X1, W1b, Yp, M, FC, K1);

  // BN1 (fused cooperative): reduce partials + stats + apply+ReLU -> X2 bf16
  {
    int P = 7;
    size_t pstride = (size_t)M * FC;
    float invM = 1.0f / M;
    const float* YpC = Yp;
    void* args[] = {(void*)&YpC, (void*)&bn1_g, (void*)&bn1_b, (void*)&X2,
                    (void*)&P, (void*)&pstride, (void*)&ps, (void*)&pq, (void*)&invM};
    hipLaunchCooperativeKernel((void*)bn_fused_kernel, dim3(512), dim3(256), args, 0, stream);
  }

  // fc2: X2 @ W2^T -> Yp (4 partials)
  gemm_bt_swz<4><<<dim3(M / 128, FC / 128, 4), 256, 0, stream>>>(X2, W2b, Yp, M, FC, FC);

  // BN2 (fused cooperative) -> X3 bf16
  {
    int P = 4;
    size_t pstride = (size_t)M * FC;
    float invM = 1.0f / M;
    const float* YpC = Yp;
    void* args[] = {(void*)&YpC, (void*)&bn2_g, (void*)&bn2_b, (void*)&X3,
                    (void*)&P, (void*)&pstride, (void*)&ps, (void*)&pq, (void*)&invM};
    hipLaunchCooperativeKernel((void*)bn_fused_kernel, dim3(512), dim3(256), args, 0, stream);
  }

  // pred head: X3 @ W3p^T -> Y3 (split-K=4 partials of 2048 x 96)
  gemm_bt_kernel<64, 96, 2, 2, 4><<<dim3(M / 64, 1, 4), 256, 0, stream>>>(X3, W3b, Y3, M, 96, FC);

  // decode -> out (2048 x 94)
  decode_kernel<<<(2048 * 94 + 255) / 256, 256, 0, stream>>>(Y3, pred_b, anchors, anchor_id, out);
}

// Round 16
// 278.457 us; speedup vs baseline: 1.3527x; 1.3527x over previous
//
#include <hip/hip_runtime.h>
#include <hip/hip_bf16.h>

typedef __attribute__((ext_vector_type(8))) short short8;
typedef __attribute__((ext_vector_type(4))) float floatx4;
typedef __attribute__((ext_vector_type(4))) unsigned short ushort4v;

#define DEVI __device__ __forceinline__

// ---------------- constants ----------------
// B=4, N=512, C_IN=256, RES=7, SR=2, FC_DIM=1024, OUT_CH=94
// M = B*N = 2048 rows, K1 = 256*7*7 = 12544

DEVI unsigned short f2bf(float v) {
  union { __hip_bfloat16 h; unsigned short u; } cv;
  cv.h = __float2bfloat16(v);
  return cv.u;
}
DEVI short f2bfs(float v) { return (short)f2bf(v); }

DEVI void gload16(const void* gptr, void* lptr) {
  __builtin_amdgcn_global_load_lds(
      (const __attribute__((address_space(1))) unsigned int*)gptr,
      (__attribute__((address_space(3))) unsigned int*)(unsigned long long)(uintptr_t)lptr,
      16, 0, 0);
}

// ---------------- fused prep + ROI align ----------------
#define ROI_BLKS   16384
#define CVT1_END   28928
#define CVT2_END   29952
#define GRID_TOTAL 30336

__global__ __launch_bounds__(256) void prep_roi_kernel(
    const float* __restrict__ p3, const float* __restrict__ p4,
    const float* __restrict__ p5, const float* __restrict__ bbox,
    const int* __restrict__ aid, unsigned short* __restrict__ X,
    const float* __restrict__ fc1_w, unsigned short* __restrict__ W1b,
    const float* __restrict__ fc2_w, unsigned short* __restrict__ W2b,
    const float* __restrict__ pred_w, unsigned short* __restrict__ W3b) {
  constexpr int PS = 260;   // slow: f32 per-channel stride
  constexpr int PBS = 280;  // slow: bf16 per-channel stride (560 B)
  constexpr int PS8 = 260;  // fast: f32 per-GROUP(4ch) stride
  constexpr int PBS8 = 72;  // fast: bf16 per-channel stride (144 B)
  __shared__ float Pf[32 * PS];            // 33280 B; Pb overlays it
  __shared__ float wyx[238];               // wy [7][17] @0, wx [7][17] @119
  __shared__ int sy0[14], sx0[14];
  __shared__ float sly[14], slx[14];

  const int bid = blockIdx.x;
  const int tid = threadIdx.x;

  if (bid >= ROI_BLKS) {
    if (bid < CVT1_END) {
      size_t i = (size_t)(bid - ROI_BLKS) * 256 + tid;
      float4 v = ((const float4*)fc1_w)[i];
      ushort4v o;
      o[0] = f2bf(v.x); o[1] = f2bf(v.y); o[2] = f2bf(v.z); o[3] = f2bf(v.w);
      ((ushort4v*)W1b)[i] = o;
    } else if (bid < CVT2_END) {
      size_t i = (size_t)(bid - CVT1_END) * 256 + tid;
      float4 v = ((const float4*)fc2_w)[i];
      ushort4v o;
      o[0] = f2bf(v.x); o[1] = f2bf(v.y); o[2] = f2bf(v.z); o[3] = f2bf(v.w);
      ((ushort4v*)W2b)[i] = o;
    } else {
      int i = (bid - CVT2_END) * 256 + tid;
      int row = i >> 10;
      W3b[i] = (row < 94) ? f2bf(pred_w[i]) : (unsigned short)0;
    }
    return;
  }

  // ---------------- ROI branch ----------------
  unsigned short* Pb = (unsigned short*)Pf;
  const int box = bid & 2047;
  const int oct = bid >> 11;               // channels oct*32 ..
  const int b = box >> 9;
  const int lane = tid & 63, wid = tid >> 6;

  const int lvl = aid[box] / 3;
  const int H = 64 >> lvl;
  const int HH = H * H;
  const float* base = (lvl == 0) ? p3 : ((lvl == 1) ? p4 : p5);
  const float scale = 0.125f / (float)(1 << lvl);

  // ---- phase A: sample grid ----
  if (tid < 28) {
    int s = tid;
    bool isY = s < 14;
    int k = isY ? s : s - 14;
    float lo = bbox[box * 4 + (isY ? 0 : 1)];
    float hi = bbox[box * 4 + (isY ? 2 : 3)];
    float t = lo * scale - 0.5f;
    float cell = (hi - lo) * scale * (1.0f / 7.0f);
    float pos = t + ((float)k + 0.5f) * 0.5f * cell;   // S=14 samples, SR=2
    pos = fminf(fmaxf(pos, 0.0f), (float)(H - 1));
    int i0 = (int)floorf(pos);
    if (i0 > H - 2) i0 = H - 2;        // fr=1 reproduces the clamp
    float fr = pos - (float)i0;
    if (isY) { sy0[k] = i0; sly[k] = fr; }
    else     { sx0[k] = i0; slx[k] = fr; }
  }
  __syncthreads();

  // fast path iff the whole sample footprint (incl. +1 taps) fits an 8x8 patch
  const int ry8 = min(sy0[0], H - 8), rx8 = min(sx0[0], H - 8);
  const bool fast = (sy0[13] - ry8 <= 6) && (sx0[13] - rx8 <= 6);
  const int ryb = fast ? ry8 : min(sy0[0], H - 16);
  const int rxb = fast ? rx8 : min(sx0[0], H - 16);
  const float* fb = base + ((size_t)b * 256 + oct * 32) * HH + ryb * H + rxb;

  // ---- phase B1: separable pooled weights wy[7][16], wx[7][16] (stride 17) ----
  if (tid < 224) {
    int j = tid;
    bool isY = j < 112;
    int k2 = isY ? j : j - 112;
    int py = k2 >> 4, r = k2 & 15;
    int o0 = isY ? ryb : rxb;
    float acc = 0.f;
#pragma unroll
    for (int ss = 0; ss < 2; ++ss) {
      int s = 2 * py + ss;
      int rel = (isY ? sy0[s] : sx0[s]) - o0;
      float fr = isY ? sly[s] : slx[s];
      if (r == rel)     acc += 1.0f - fr;
      if (r == rel + 1) acc += fr;
    }
    wyx[(isY ? 0 : 119) + py * 17 + r] = acc * 0.5f;
  }

  const int fr = lane & 15, fg = lane >> 4;
  const int cell = wid * 16 + fr;          // 0..63; valid < 49
  const int py = (cell * 37) >> 8;         // cell/7 for 0..63 (py<=9: garbage, masked)
  const int px = cell - py * 7;

  floatx4 acc0 = (floatx4){0.f, 0.f, 0.f, 0.f};   // channels 0..15
  floatx4 acc1 = (floatx4){0.f, 0.f, 0.f, 0.f};   // channels 16..31

  if (fast) {
    // ---- FAST: 8x8 patch, K=64 ----
    {
      const int r8 = (lane & 15) >> 1, c8 = (lane & 1) * 4, lch = lane >> 4;
      const float* s8 = fb + r8 * H + c8;
#pragma unroll
      for (int it = 0; it < 2; ++it) {
        int grp = it * 4 + wid;
        gload16(s8 + (size_t)(grp * 4 + lch) * HH, &Pf[grp * PS8] + lane * 4);
      }
    }
    __syncthreads();

    {
      const int cch = tid & 31, hf = tid >> 5;
      const float* src = &Pf[(cch >> 2) * PS8 + (cch & 3) * 64 + hf * 8];
      floatx4 v0 = *(const floatx4*)src, v1 = *(const floatx4*)(src + 4);
      __syncthreads();
      unsigned int d0 = (unsigned int)f2bf(v0[0]) | ((unsigned int)f2bf(v0[1]) << 16);
      unsigned int d1 = (unsigned int)f2bf(v0[2]) | ((unsigned int)f2bf(v0[3]) << 16);
      unsigned int d2 = (unsigned int)f2bf(v1[0]) | ((unsigned int)f2bf(v1[1]) << 16);
      unsigned int d3 = (unsigned int)f2bf(v1[2]) | ((unsigned int)f2bf(v1[3]) << 16);
      *(uint4*)&Pb[cch * PBS8 + hf * 8] = make_uint4(d0, d1, d2, d3);
    }

    float xv[8];
    const float* xp = &wyx[119 + px * 17];
#pragma unroll
    for (int e = 0; e < 8; ++e) xv[e] = xp[e];
    const float w0 = wyx[py * 17 + fg];
    const float w1 = wyx[py * 17 + 4 + fg];
    __syncthreads();

#pragma unroll
    for (int kk = 0; kk < 2; ++kk) {
      short8 af0 = *(const short8*)&Pb[fr * PBS8 + kk * 32 + fg * 8];
      short8 af1 = *(const short8*)&Pb[(16 + fr) * PBS8 + kk * 32 + fg * 8];
      short8 bfr;
      const float w = kk ? w1 : w0;
#pragma unroll
      for (int e = 0; e < 8; ++e) bfr[e] = f2bfs(w * xv[e]);
      acc0 = __builtin_amdgcn_mfma_f32_16x16x32_bf16(af0, bfr, acc0, 0, 0, 0);
      acc1 = __builtin_amdgcn_mfma_f32_16x16x32_bf16(af1, bfr, acc1, 0, 0, 0);
    }
  } else {
    // ---- SLOW: 16x16 patch, K=256 ----
    {
      const int r = lane >> 2, c4 = (lane & 3) * 4;
      const float* src0 = fb + r * H + c4;
#pragma unroll
      for (int it = 0; it < 8; ++it) {
        int ch = it * 4 + wid;
        gload16(src0 + (size_t)ch * HH, &Pf[ch * PS] + lane * 4);
      }
    }
    __syncthreads();

    {
      const int cch = tid & 31, rp = tid >> 5;
      const float* src = &Pf[cch * PS + rp * 32];
      floatx4 v[8];
#pragma unroll
      for (int m = 0; m < 8; ++m) v[m] = *(const floatx4*)(src + 4 * m);
      __syncthreads();
      unsigned int d[16];
#pragma unroll
      for (int m = 0; m < 8; ++m) {
        d[2 * m]     = (unsigned int)f2bf(v[m][0]) | ((unsigned int)f2bf(v[m][1]) << 16);
        d[2 * m + 1] = (unsigned int)f2bf(v[m][2]) | ((unsigned int)f2bf(v[m][3]) << 16);
      }
      unsigned short* dst = &Pb[cch * PBS + rp * 32];
#pragma unroll
      for (int m = 0; m < 4; ++m)
        *(uint4*)(dst + m * 8) = make_uint4(d[4 * m], d[4 * m + 1], d[4 * m + 2], d[4 * m + 3]);
    }

    float xv[8], wyv[8];
    {
      const float* xp = &wyx[119 + px * 17 + (fg & 1) * 8];
#pragma unroll
      for (int e = 0; e < 8; ++e) xv[e] = xp[e];
      const float* wp = &wyx[py * 17 + (fg >> 1)];
#pragma unroll
      for (int kk = 0; kk < 8; ++kk) wyv[kk] = wp[2 * kk];
    }
    __syncthreads();

#pragma unroll
    for (int kk = 0; kk < 8; ++kk) {
      short8 af0 = *(const short8*)&Pb[fr * PBS + kk * 32 + fg * 8];
      short8 af1 = *(const short8*)&Pb[(16 + fr) * PBS + kk * 32 + fg * 8];
      short8 bfr;
      const float w = wyv[kk];
#pragma unroll
      for (int e = 0; e < 8; ++e) bfr[e] = f2bfs(w * xv[e]);
      acc0 = __builtin_amdgcn_mfma_f32_16x16x32_bf16(af0, bfr, acc0, 0, 0, 0);
      acc1 = __builtin_amdgcn_mfma_f32_16x16x32_bf16(af1, bfr, acc1, 0, 0, 0);
    }
  }

  if (cell < 49) {
    unsigned short* xb = X + (size_t)box * 12544 + (size_t)(oct * 32) * 49 + cell;
#pragma unroll
    for (int q = 0; q < 4; ++q) {
      xb[(fg * 4 + q) * 49] = f2bf(acc0[q]);
      xb[(16 + fg * 4 + q) * 49] = f2bf(acc1[q]);
    }
  }
}

// ---------------- GEMM: 128x128 tile, BK=64, T2 XOR-swizzle, split-K, T1 XCD swizzle ----------------
template <int KSPLIT>
__global__ __launch_bounds__(256) void gemm_bt_swz(
    const unsigned short* __restrict__ A, const unsigned short* __restrict__ Bw,
    float* __restrict__ C, int M, int N, int K) {
  constexpr int BM = 128, BN = 128, BK = 64;
  __shared__ unsigned short As[BM * BK];   // 16 KB
  __shared__ unsigned short Bs[BN * BK];   // 16 KB

  const int tid = threadIdx.x;
  const int lane = tid & 63, wid = tid >> 6;
  const int wr = wid >> 1, wc = wid & 1;    // 2x2 waves, 64x64 each
  const int fr = lane & 15, fg = lane >> 4;

  // T1: XCD-aware block swizzle (bijective since nwg % 8 == 0)
  int bx = blockIdx.x, by = blockIdx.y, bz = blockIdx.z;
  {
    const int gx = gridDim.x, gy = gridDim.y;
    const int nwg = gx * gy * gridDim.z;
    if ((nwg & 7) == 0) {
      int lin = bx + gx * (by + gy * bz);
      int swz = (lin & 7) * (nwg >> 3) + (lin >> 3);
      bx = swz % gx;
      int t = swz / gx;
      by = t % gy;
      bz = t / gy;
    }
  }
  const int tm = bx * BM, tn = by * BN;

  const int kLen = K / KSPLIT;
  const int kTiles = kLen / BK;
  const int kBeg = bz * kLen;
  float* Cz = C + (size_t)bz * M * N;

  floatx4 acc[4][4];
#pragma unroll
  for (int i = 0; i < 4; ++i)
#pragma unroll
    for (int j = 0; j < 4; ++j)
      acc[i][j] = (floatx4){0.f, 0.f, 0.f, 0.f};

  for (int t = 0; t < kTiles; ++t) {
    const int k0 = kBeg + t * BK;
#pragma unroll
    for (int s = tid; s < BM * 8; s += 256) {
      int row = s >> 3, sl = s & 7;
      int slg = sl ^ (row & 7);
      gload16(&A[(size_t)(tm + row) * K + k0 + slg * 8], &As[s * 8]);
    }
#pragma unroll
    for (int s = tid; s < BN * 8; s += 256) {
      int row = s >> 3, sl = s & 7;
      int slg = sl ^ (row & 7);
      gload16(&Bw[(size_t)(tn + row) * K + k0 + slg * 8], &Bs[s * 8]);
    }
    __syncthreads();

#pragma unroll
    for (int kk = 0; kk < 2; ++kk) {
      short8 af[4], bf[4];
#pragma unroll
      for (int i = 0; i < 4; ++i) {
        int row = wr * 64 + i * 16 + fr;
        int sl = (kk * 4 + fg) ^ (row & 7);
        af[i] = *reinterpret_cast<const short8*>(&As[(row * 8 + sl) * 8]);
      }
#pragma unroll
      for (int j = 0; j < 4; ++j) {
        int row = wc * 64 + j * 16 + fr;
        int sl = (kk * 4 + fg) ^ (row & 7);
        bf[j] = *reinterpret_cast<const short8*>(&Bs[(row * 8 + sl) * 8]);
      }
#pragma unroll
      for (int i = 0; i < 4; ++i)
#pragma unroll
        for (int j = 0; j < 4; ++j)
          acc[i][j] = __builtin_amdgcn_mfma_f32_16x16x32_bf16(af[i], bf[j], acc[i][j], 0, 0, 0);
    }
    __syncthreads();
  }

#pragma unroll
  for (int i = 0; i < 4; ++i)
#pragma unroll
    for (int j = 0; j < 4; ++j)
#pragma unroll
      for (int q = 0; q < 4; ++q) {
        int rr = tm + wr * 64 + i * 16 + fg * 4 + q;
        int cc = tn + wc * 64 + j * 16 + fr;
        Cz[(size_t)rr * N + cc] = acc[i][j][q];
      }
}

// ---------------- old GEMM (pred head only) ----------------
template <int BM, int BN, int WAVES_M, int WAVES_N, int KSPLIT>
__global__ __launch_bounds__(256) void gemm_bt_kernel(
    const unsigned short* __restrict__ A, const unsigned short* __restrict__ Bw,
    float* __restrict__ C, int M, int N, int K) {
  constexpr int BK = 32;
  constexpr int WM = BM / WAVES_M, WN = BN / WAVES_N;
  constexpr int AF = WM / 16, BF = WN / 16;
  constexpr int ASLOT = BM * 4;
  constexpr int BSLOT = BN * 4;
  __shared__ unsigned short As[BM * BK];
  __shared__ unsigned short Bs[BN * BK];

  const int tid = threadIdx.x;
  const int lane = tid & 63, wid = tid >> 6;
  const int wr = wid / WAVES_N, wc = wid % WAVES_N;
  const int tm = blockIdx.x * BM, tn = blockIdx.y * BN;
  const int fr = lane & 15, fg = lane >> 4;

  const int kLen = K / KSPLIT;
  const int kBeg = blockIdx.z * kLen;
  float* Cz = C + (size_t)blockIdx.z * M * N;

  floatx4 acc[AF][BF];
#pragma unroll
  for (int i = 0; i < AF; ++i)
#pragma unroll
    for (int j = 0; j < BF; ++j)
      acc[i][j] = (floatx4){0.f, 0.f, 0.f, 0.f};

  for (int k0 = kBeg; k0 < kBeg + kLen; k0 += BK) {
#pragma unroll
    for (int s = tid; s < ASLOT; s += 256) {
      int row = s >> 2, kb = (s & 3) << 3;
      gload16(&A[(size_t)(tm + row) * K + k0 + kb], &As[s * 8]);
    }
#pragma unroll
    for (int s = tid; s < BSLOT; s += 256) {
      int row = s >> 2, kb = (s & 3) << 3;
      gload16(&Bw[(size_t)(tn + row) * K + k0 + kb], &Bs[s * 8]);
    }
    __syncthreads();

    short8 af[AF], bfv[BF];
#pragma unroll
    for (int i = 0; i < AF; ++i)
      af[i] = *reinterpret_cast<const short8*>(&As[(wr * WM + i * 16 + fr) * BK + fg * 8]);
#pragma unroll
    for (int j = 0; j < BF; ++j)
      bfv[j] = *reinterpret_cast<const short8*>(&Bs[(wc * WN + j * 16 + fr) * BK + fg * 8]);
#pragma unroll
    for (int i = 0; i < AF; ++i)
#pragma unroll
      for (int j = 0; j < BF; ++j)
        acc[i][j] = __builtin_amdgcn_mfma_f32_16x16x32_bf16(af[i], bfv[j], acc[i][j], 0, 0, 0);
    __syncthreads();
  }

#pragma unroll
  for (int i = 0; i < AF; ++i)
#pragma unroll
    for (int j = 0; j < BF; ++j)
#pragma unroll
      for (int q = 0; q < 4; ++q) {
        int rr = tm + wr * WM + i * 16 + fg * 4 + q;
        int cc = tn + wc * WN + j * 16 + fr;
        Cz[(size_t)rr * N + cc] = acc[i][j][q];
      }
}

// ---------------- BatchNorm (train mode) ----------------
// pass 1: reduce split-K partials + per-rowgroup stats. grid (Ncols/256, 128).
__global__ void bn_stats_red_kernel(const float* __restrict__ Yp, float* __restrict__ Yred,
                                    float* __restrict__ psum, float* __restrict__ psq,
                                    int Ncols, int rowsPer, int P, size_t pstride) {
  int c = blockIdx.x * blockDim.x + threadIdx.x;
  int r0 = blockIdx.y * rowsPer;
  float s = 0.f, ss = 0.f;
  for (int r = 0; r < rowsPer; ++r) {
    size_t idx = (size_t)(r0 + r) * Ncols + c;
    float v = Yp[idx];
    for (int p = 1; p < P; ++p) v += Yp[idx + (size_t)p * pstride];
    Yred[idx] = v;
    s += v;
    ss += v * v;
  }
  psum[(size_t)blockIdx.y * Ncols + c] = s;
  psq[(size_t)blockIdx.y * Ncols + c] = ss;
}

__global__ void bn_finalize_kernel(const float* __restrict__ psum, const float* __restrict__ psq,
                                   const float* __restrict__ g, const float* __restrict__ b,
                                   float* __restrict__ scale, float* __restrict__ shift,
                                   int Ncols, int P, float invM) {
  int c = blockIdx.x * blockDim.x + threadIdx.x;
  if (c >= Ncols) return;
  float s = 0.f, ss = 0.f;
  for (int p = 0; p < P; ++p) {
    s += psum[(size_t)p * Ncols + c];
    ss += psq[(size_t)p * Ncols + c];
  }
  float mean = s * invM;
  float var = ss * invM - mean * mean;
  float rstd = rsqrtf(var + 1e-5f);
  float sc = rstd * g[c];
  scale[c] = sc;
  shift[c] = b[c] - mean * sc;
}

__global__ void bn_apply4_kernel(const float4* __restrict__ Y, const float* __restrict__ scale,
                                 const float* __restrict__ shift, ushort4v* __restrict__ X,
                                 int colGroupsMask, int total4) {
  int i = blockIdx.x * blockDim.x + threadIdx.x;
  if (i >= total4) return;
  int c0 = (i & colGroupsMask) * 4;
  float4 v = Y[i];
  ushort4v o;
  o[0] = f2bf(fmaxf(v.x * scale[c0 + 0] + shift[c0 + 0], 0.0f));
  o[1] = f2bf(fmaxf(v.y * scale[c0 + 1] + shift[c0 + 1], 0.0f));
  o[2] = f2bf(fmaxf(v.z * scale[c0 + 2] + shift[c0 + 2], 0.0f));
  o[3] = f2bf(fmaxf(v.w * scale[c0 + 3] + shift[c0 + 3], 0.0f));
  X[i] = o;
}

// ---------------- decode ----------------
__global__ void decode_kernel(const float* __restrict__ Y3, const float* __restrict__ pb,
                              const float* __restrict__ anchors, const int* __restrict__ aid,
                              float* __restrict__ out) {
  int i = blockIdx.x * blockDim.x + threadIdx.x;
  if (i >= 2048 * 94) return;
  int bn = i / 94;
  int ch = i - bn * 94;
  size_t idx = (size_t)bn * 96 + ch;
  float v = Y3[idx] + Y3[idx + 2048 * 96] + Y3[idx + 2 * 2048 * 96] + Y3[idx + 3 * 2048 * 96];
  v += pb[ch];
  float o = v;
  if (ch >= 4 && ch < 22) {
    int q = ch - 4;
    int d = q % 6;   // within-class: 0,1=yx 2,3=lw 4,5=zh
    if (d < 2) {
      float stride_px = (float)(8 << (aid[bn] / 3));
      o = anchors[(size_t)bn * 4 + d] + v * stride_px;
    } else if (d < 4) {
      float cl = fminf(fmaxf(v, -4.0f), 4.0f);
      o = anchors[(size_t)bn * 4 + d] * expf(cl);
    }
  }
  out[i] = o;
}

// ---------------- launch ----------------
extern "C" void kernel_launch(void* const* d_in, const int* in_sizes, int n_in,
                              void* d_out, int out_size, void* d_ws, size_t ws_size,
                              hipStream_t stream) {
  const float* feat_p3   = (const float*)d_in[0];
  const float* feat_p4   = (const float*)d_in[1];
  const float* feat_p5   = (const float*)d_in[2];
  const float* bbox2d    = (const float*)d_in[3];
  const float* anchors   = (const float*)d_in[4];
  const int*   anchor_id = (const int*)d_in[5];
  const float* fc1_w     = (const float*)d_in[6];
  // d_in[7] fc1_b: cancels through train-mode BN (mean subtraction) — unused
  const float* bn1_g     = (const float*)d_in[8];
  const float* bn1_b     = (const float*)d_in[9];
  const float* fc2_w     = (const float*)d_in[10];
  // d_in[11] fc2_b: cancels — unused
  const float* bn2_g     = (const float*)d_in[12];
  const float* bn2_b     = (const float*)d_in[13];
  const float* pred_w    = (const float*)d_in[14];
  const float* pred_b    = (const float*)d_in[15];
  float* out = (float*)d_out;

  const int M = 2048;          // B*N
  const int K1 = 12544;        // 256*7*7
  const int FC = 1024;
  const int RG = 128;          // BN stats row-groups

  char* ws = (char*)d_ws;
  auto alloc = [&](size_t bytes) -> char* {
    char* p = ws;
    ws += (bytes + 255) & ~(size_t)255;
    return p;
  };
  unsigned short* W1b  = (unsigned short*)alloc((size_t)FC * K1 * 2);
  unsigned short* W2b  = (unsigned short*)alloc((size_t)FC * FC * 2);
  unsigned short* W3b  = (unsigned short*)alloc((size_t)96 * FC * 2);
  unsigned short* X1   = (unsigned short*)alloc((size_t)M * K1 * 2);
  float*          Yp   = (float*)alloc((size_t)7 * M * FC * 4);  // split-K partials (fc1: 7, fc2: 4)
  float*          Yr   = (float*)alloc((size_t)M * FC * 4);      // reduced Y
  unsigned short* X2   = (unsigned short*)alloc((size_t)M * FC * 2);
  unsigned short* X3   = (unsigned short*)alloc((size_t)M * FC * 2);
  float*          Y3   = (float*)alloc((size_t)4 * M * 96 * 4);
  float*          ps   = (float*)alloc((size_t)RG * FC * 4);
  float*          pq   = (float*)alloc((size_t)RG * FC * 4);
  float*          sc1  = (float*)alloc((size_t)FC * 4);
  float*          sh1  = (float*)alloc((size_t)FC * 4);
  float*          sc2  = (float*)alloc((size_t)FC * 4);
  float*          sh2  = (float*)alloc((size_t)FC * 4);

  // fused: weight conversions (overlapped) + ROI align -> X1
  prep_roi_kernel<<<GRID_TOTAL, 256, 0, stream>>>(
      feat_p3, feat_p4, feat_p5, bbox2d, anchor_id, X1,
      fc1_w, W1b, fc2_w, W2b, pred_w, W3b);

  // fc1: X1 (2048x12544) @ W1^T -> Yp (7 partials; 12544 = 64*196, 196 = 7*28)
  gemm_bt_swz<7><<<dim3(M / 128, FC / 128, 7), 256, 0, stream>>>(X1, W1b, Yp, M, FC, K1);

  // BN1: reduce 7 partials + stats (512 blocks), finalize, apply+ReLU -> X2 bf16
  bn_stats_red_kernel<<<dim3(FC / 256, RG), 256, 0, stream>>>(Yp, Yr, ps, pq, FC, M / RG, 7, (size_t)M * FC);
  bn_finalize_kernel<<<FC / 256, 256, 0, stream>>>(ps, pq, bn1_g, bn1_b, sc1, sh1, FC, RG, 1.0f / M);
  bn_apply4_kernel<<<(M * FC / 4) / 256, 256, 0, stream>>>(
      (const float4*)Yr, sc1, sh1, (ushort4v*)X2, FC / 4 - 1, M * FC / 4);

  // fc2: X2 @ W2^T -> Yp (4 partials)
  gemm_bt_swz<4><<<dim3(M / 128, FC / 128, 4), 256, 0, stream>>>(X2, W2b, Yp, M, FC, FC);

  // BN2 + ReLU -> X3 bf16
  bn_stats_red_kernel<<<dim3(FC / 256, RG), 256, 0, stream>>>(Yp, Yr, ps, pq, FC, M / RG, 4, (size_t)M * FC);
  bn_finalize_kernel<<<FC / 256, 256, 0, stream>>>(ps, pq, bn2_g, bn2_b, sc2, sh2, FC, RG, 1.0f / M);
  bn_apply4_kernel<<<(M * FC / 4) / 256, 256, 0, stream>>>(
      (const float4*)Yr, sc2, sh2, (ushort4v*)X3, FC / 4 - 1, M * FC / 4);

  // pred head: X3 @ W3p^T -> Y3 (split-K=4 partials of 2048 x 96)
  gemm_bt_kernel<64, 96, 2, 2, 4><<<dim3(M / 64, 1, 4), 256, 0, stream>>>(X3, W3b, Y3, M, 96, FC);

  // decode -> out (2048 x 94)
  decode_kernel<<<(2048 * 94 + 255) / 256, 256, 0, stream>>>(Y3, pred_b, anchors, anchor_id, out);
}

// Round 17
// 243.373 us; speedup vs baseline: 1.5477x; 1.1442x over previous
//
#include <hip/hip_runtime.h>
#include <hip/hip_bf16.h>

typedef __attribute__((ext_vector_type(8))) short short8;
typedef __attribute__((ext_vector_type(4))) float floatx4;
typedef __attribute__((ext_vector_type(4))) unsigned short ushort4v;

#define DEVI __device__ __forceinline__

// ---------------- constants ----------------
// B=4, N=512, C_IN=256, RES=7, SR=2, FC_DIM=1024, OUT_CH=94
// M = B*N = 2048 rows, K1 = 256*7*7 = 12544

DEVI unsigned short f2bf(float v) {
  union { __hip_bfloat16 h; unsigned short u; } cv;
  cv.h = __float2bfloat16(v);
  return cv.u;
}
DEVI short f2bfs(float v) { return (short)f2bf(v); }

DEVI void gload16(const void* gptr, void* lptr) {
  __builtin_amdgcn_global_load_lds(
      (const __attribute__((address_space(1))) unsigned int*)gptr,
      (__attribute__((address_space(3))) unsigned int*)(unsigned long long)(uintptr_t)lptr,
      16, 0, 0);
}

// ---------------- fused prep + ROI align ----------------
// Block ranges (uniform branch per block):
//   [0, 16384)          : ROI align, box = bid&2047, oct = bid>>11
//   [16384, 28928)      : cvt fc1_w f32->bf16
//   [28928, 29952)      : cvt fc2_w f32->bf16
//   [29952, 30336)      : pred_w pad-cvt
// ROI has two per-block-uniform paths: 16x16 patch (K=256) and, when the
// sample span fits, an 8x8 patch (K=64) — 1/4 the staging and MFMA work.
#define ROI_BLKS   16384
#define CVT1_END   28928
#define CVT2_END   29952
#define GRID_TOTAL 30336

__global__ __launch_bounds__(256) void prep_roi_kernel(
    const float* __restrict__ p3, const float* __restrict__ p4,
    const float* __restrict__ p5, const float* __restrict__ bbox,
    const int* __restrict__ aid, unsigned short* __restrict__ X,
    const float* __restrict__ fc1_w, unsigned short* __restrict__ W1b,
    const float* __restrict__ fc2_w, unsigned short* __restrict__ W2b,
    const float* __restrict__ pred_w, unsigned short* __restrict__ W3b) {
  constexpr int PS = 260;   // slow: f32 per-channel stride
  constexpr int PBS = 280;  // slow: bf16 per-channel stride (560 B)
  constexpr int PS8 = 260;  // fast: f32 per-GROUP(4ch) stride
  constexpr int PBS8 = 72;  // fast: bf16 per-channel stride (144 B)
  __shared__ float Pf[32 * PS];            // 33280 B; Pb overlays it
  __shared__ float wyx[238];               // wy [7][17] @0, wx [7][17] @119
  __shared__ int sy0[14], sx0[14];
  __shared__ float sly[14], slx[14];

  const int bid = blockIdx.x;
  const int tid = threadIdx.x;

  if (bid >= ROI_BLKS) {
    if (bid < CVT1_END) {
      size_t i = (size_t)(bid - ROI_BLKS) * 256 + tid;
      float4 v = ((const float4*)fc1_w)[i];
      ushort4v o;
      o[0] = f2bf(v.x); o[1] = f2bf(v.y); o[2] = f2bf(v.z); o[3] = f2bf(v.w);
      ((ushort4v*)W1b)[i] = o;
    } else if (bid < CVT2_END) {
      size_t i = (size_t)(bid - CVT1_END) * 256 + tid;
      float4 v = ((const float4*)fc2_w)[i];
      ushort4v o;
      o[0] = f2bf(v.x); o[1] = f2bf(v.y); o[2] = f2bf(v.z); o[3] = f2bf(v.w);
      ((ushort4v*)W2b)[i] = o;
    } else {
      int i = (bid - CVT2_END) * 256 + tid;
      int row = i >> 10;
      W3b[i] = (row < 94) ? f2bf(pred_w[i]) : (unsigned short)0;
    }
    return;
  }

  // ---------------- ROI branch ----------------
  unsigned short* Pb = (unsigned short*)Pf;
  const int box = bid & 2047;
  const int oct = bid >> 11;               // channels oct*32 ..
  const int b = box >> 9;
  const int lane = tid & 63, wid = tid >> 6;

  const int lvl = aid[box] / 3;
  const int H = 64 >> lvl;
  const int HH = H * H;
  const float* base = (lvl == 0) ? p3 : ((lvl == 1) ? p4 : p5);
  const float scale = 0.125f / (float)(1 << lvl);

  // ---- phase A: sample grid ----
  if (tid < 28) {
    int s = tid;
    bool isY = s < 14;
    int k = isY ? s : s - 14;
    float lo = bbox[box * 4 + (isY ? 0 : 1)];
    float hi = bbox[box * 4 + (isY ? 2 : 3)];
    float t = lo * scale - 0.5f;
    float cell = (hi - lo) * scale * (1.0f / 7.0f);
    float pos = t + ((float)k + 0.5f) * 0.5f * cell;   // S=14 samples, SR=2
    pos = fminf(fmaxf(pos, 0.0f), (float)(H - 1));
    int i0 = (int)floorf(pos);
    if (i0 > H - 2) i0 = H - 2;        // fr=1 reproduces the clamp
    float fr = pos - (float)i0;
    if (isY) { sy0[k] = i0; sly[k] = fr; }
    else     { sx0[k] = i0; slx[k] = fr; }
  }
  __syncthreads();

  // fast path iff the whole sample footprint (incl. +1 taps) fits an 8x8 patch
  const int ry8 = min(sy0[0], H - 8), rx8 = min(sx0[0], H - 8);
  const bool fast = (sy0[13] - ry8 <= 6) && (sx0[13] - rx8 <= 6);
  const int ryb = fast ? ry8 : min(sy0[0], H - 16);
  const int rxb = fast ? rx8 : min(sx0[0], H - 16);
  const float* fb = base + ((size_t)b * 256 + oct * 32) * HH + ryb * H + rxb;

  // ---- phase B1: separable pooled weights wy[7][16], wx[7][16] (stride 17) ----
  if (tid < 224) {
    int j = tid;
    bool isY = j < 112;
    int k2 = isY ? j : j - 112;
    int py = k2 >> 4, r = k2 & 15;
    int o0 = isY ? ryb : rxb;
    float acc = 0.f;
#pragma unroll
    for (int ss = 0; ss < 2; ++ss) {
      int s = 2 * py + ss;
      int rel = (isY ? sy0[s] : sx0[s]) - o0;
      float fr = isY ? sly[s] : slx[s];
      if (r == rel)     acc += 1.0f - fr;
      if (r == rel + 1) acc += fr;
    }
    wyx[(isY ? 0 : 119) + py * 17 + r] = acc * 0.5f;
  }

  const int fr = lane & 15, fg = lane >> 4;
  const int cell = wid * 16 + fr;          // 0..63; valid < 49
  const int py = (cell * 37) >> 8;         // cell/7 for 0..63 (py<=9: garbage, masked)
  const int px = cell - py * 7;

  floatx4 acc0 = (floatx4){0.f, 0.f, 0.f, 0.f};   // channels 0..15
  floatx4 acc1 = (floatx4){0.f, 0.f, 0.f, 0.f};   // channels 16..31

  if (fast) {
    // ---- FAST: 8x8 patch, K=64 ----
    {
      const int r8 = (lane & 15) >> 1, c8 = (lane & 1) * 4, lch = lane >> 4;
      const float* s8 = fb + r8 * H + c8;
#pragma unroll
      for (int it = 0; it < 2; ++it) {
        int grp = it * 4 + wid;
        gload16(s8 + (size_t)(grp * 4 + lch) * HH, &Pf[grp * PS8] + lane * 4);
      }
    }
    __syncthreads();

    {
      const int cch = tid & 31, hf = tid >> 5;
      const float* src = &Pf[(cch >> 2) * PS8 + (cch & 3) * 64 + hf * 8];
      floatx4 v0 = *(const floatx4*)src, v1 = *(const floatx4*)(src + 4);
      __syncthreads();
      unsigned int d0 = (unsigned int)f2bf(v0[0]) | ((unsigned int)f2bf(v0[1]) << 16);
      unsigned int d1 = (unsigned int)f2bf(v0[2]) | ((unsigned int)f2bf(v0[3]) << 16);
      unsigned int d2 = (unsigned int)f2bf(v1[0]) | ((unsigned int)f2bf(v1[1]) << 16);
      unsigned int d3 = (unsigned int)f2bf(v1[2]) | ((unsigned int)f2bf(v1[3]) << 16);
      *(uint4*)&Pb[cch * PBS8 + hf * 8] = make_uint4(d0, d1, d2, d3);
    }

    float xv[8];
    const float* xp = &wyx[119 + px * 17];
#pragma unroll
    for (int e = 0; e < 8; ++e) xv[e] = xp[e];
    const float w0 = wyx[py * 17 + fg];
    const float w1 = wyx[py * 17 + 4 + fg];
    __syncthreads();

#pragma unroll
    for (int kk = 0; kk < 2; ++kk) {
      short8 af0 = *(const short8*)&Pb[fr * PBS8 + kk * 32 + fg * 8];
      short8 af1 = *(const short8*)&Pb[(16 + fr) * PBS8 + kk * 32 + fg * 8];
      short8 bfr;
      const float w = kk ? w1 : w0;
#pragma unroll
      for (int e = 0; e < 8; ++e) bfr[e] = f2bfs(w * xv[e]);
      acc0 = __builtin_amdgcn_mfma_f32_16x16x32_bf16(af0, bfr, acc0, 0, 0, 0);
      acc1 = __builtin_amdgcn_mfma_f32_16x16x32_bf16(af1, bfr, acc1, 0, 0, 0);
    }
  } else {
    // ---- SLOW: 16x16 patch, K=256 ----
    {
      const int r = lane >> 2, c4 = (lane & 3) * 4;
      const float* src0 = fb + r * H + c4;
#pragma unroll
      for (int it = 0; it < 8; ++it) {
        int ch = it * 4 + wid;
        gload16(src0 + (size_t)ch * HH, &Pf[ch * PS] + lane * 4);
      }
    }
    __syncthreads();

    {
      const int cch = tid & 31, rp = tid >> 5;
      const float* src = &Pf[cch * PS + rp * 32];
      floatx4 v[8];
#pragma unroll
      for (int m = 0; m < 8; ++m) v[m] = *(const floatx4*)(src + 4 * m);
      __syncthreads();
      unsigned int d[16];
#pragma unroll
      for (int m = 0; m < 8; ++m) {
        d[2 * m]     = (unsigned int)f2bf(v[m][0]) | ((unsigned int)f2bf(v[m][1]) << 16);
        d[2 * m + 1] = (unsigned int)f2bf(v[m][2]) | ((unsigned int)f2bf(v[m][3]) << 16);
      }
      unsigned short* dst = &Pb[cch * PBS + rp * 32];
#pragma unroll
      for (int m = 0; m < 4; ++m)
        *(uint4*)(dst + m * 8) = make_uint4(d[4 * m], d[4 * m + 1], d[4 * m + 2], d[4 * m + 3]);
    }

    float xv[8], wyv[8];
    {
      const float* xp = &wyx[119 + px * 17 + (fg & 1) * 8];
#pragma unroll
      for (int e = 0; e < 8; ++e) xv[e] = xp[e];
      const float* wp = &wyx[py * 17 + (fg >> 1)];
#pragma unroll
      for (int kk = 0; kk < 8; ++kk) wyv[kk] = wp[2 * kk];
    }
    __syncthreads();

#pragma unroll
    for (int kk = 0; kk < 8; ++kk) {
      short8 af0 = *(const short8*)&Pb[fr * PBS + kk * 32 + fg * 8];
      short8 af1 = *(const short8*)&Pb[(16 + fr) * PBS + kk * 32 + fg * 8];
      short8 bfr;
      const float w = wyv[kk];
#pragma unroll
      for (int e = 0; e < 8; ++e) bfr[e] = f2bfs(w * xv[e]);
      acc0 = __builtin_amdgcn_mfma_f32_16x16x32_bf16(af0, bfr, acc0, 0, 0, 0);
      acc1 = __builtin_amdgcn_mfma_f32_16x16x32_bf16(af1, bfr, acc1, 0, 0, 0);
    }
  }

  if (cell < 49) {
    unsigned short* xb = X + (size_t)box * 12544 + (size_t)(oct * 32) * 49 + cell;
#pragma unroll
    for (int q = 0; q < 4; ++q) {
      xb[(fg * 4 + q) * 49] = f2bf(acc0[q]);
      xb[(16 + fg * 4 + q) * 49] = f2bf(acc1[q]);
    }
  }
}

// ---------------- GEMM v3: 128x128 tile, BK=64, T2 XOR-swizzle, split-K, T1 XCD swizzle ----------------
template <int KSPLIT>
__global__ __launch_bounds__(256) void gemm_bt_swz(
    const unsigned short* __restrict__ A, const unsigned short* __restrict__ Bw,
    float* __restrict__ C, int M, int N, int K) {
  constexpr int BM = 128, BN = 128, BK = 64;
  __shared__ unsigned short As[BM * BK];   // 16 KB
  __shared__ unsigned short Bs[BN * BK];   // 16 KB

  const int tid = threadIdx.x;
  const int lane = tid & 63, wid = tid >> 6;
  const int wr = wid >> 1, wc = wid & 1;    // 2x2 waves, 64x64 each
  const int fr = lane & 15, fg = lane >> 4;

  // T1: XCD-aware block swizzle (bijective since nwg % 8 == 0)
  int bx = blockIdx.x, by = blockIdx.y, bz = blockIdx.z;
  {
    const int gx = gridDim.x, gy = gridDim.y;
    const int nwg = gx * gy * gridDim.z;
    if ((nwg & 7) == 0) {
      int lin = bx + gx * (by + gy * bz);
      int swz = (lin & 7) * (nwg >> 3) + (lin >> 3);
      bx = swz % gx;
      int t = swz / gx;
      by = t % gy;
      bz = t / gy;
    }
  }
  const int tm = bx * BM, tn = by * BN;

  const int kLen = K / KSPLIT;
  const int kTiles = kLen / BK;
  const int kBeg = bz * kLen;
  float* Cz = C + (size_t)bz * M * N;

  floatx4 acc[4][4];
#pragma unroll
  for (int i = 0; i < 4; ++i)
#pragma unroll
    for (int j = 0; j < 4; ++j)
      acc[i][j] = (floatx4){0.f, 0.f, 0.f, 0.f};

  for (int t = 0; t < kTiles; ++t) {
    const int k0 = kBeg + t * BK;
#pragma unroll
    for (int s = tid; s < BM * 8; s += 256) {
      int row = s >> 3, sl = s & 7;
      int slg = sl ^ (row & 7);
      gload16(&A[(size_t)(tm + row) * K + k0 + slg * 8], &As[s * 8]);
    }
#pragma unroll
    for (int s = tid; s < BN * 8; s += 256) {
      int row = s >> 3, sl = s & 7;
      int slg = sl ^ (row & 7);
      gload16(&Bw[(size_t)(tn + row) * K + k0 + slg * 8], &Bs[s * 8]);
    }
    __syncthreads();

#pragma unroll
    for (int kk = 0; kk < 2; ++kk) {
      short8 af[4], bf[4];
#pragma unroll
      for (int i = 0; i < 4; ++i) {
        int row = wr * 64 + i * 16 + fr;
        int sl = (kk * 4 + fg) ^ (row & 7);
        af[i] = *reinterpret_cast<const short8*>(&As[(row * 8 + sl) * 8]);
      }
#pragma unroll
      for (int j = 0; j < 4; ++j) {
        int row = wc * 64 + j * 16 + fr;
        int sl = (kk * 4 + fg) ^ (row & 7);
        bf[j] = *reinterpret_cast<const short8*>(&Bs[(row * 8 + sl) * 8]);
      }
#pragma unroll
      for (int i = 0; i < 4; ++i)
#pragma unroll
        for (int j = 0; j < 4; ++j)
          acc[i][j] = __builtin_amdgcn_mfma_f32_16x16x32_bf16(af[i], bf[j], acc[i][j], 0, 0, 0);
    }
    __syncthreads();
  }

#pragma unroll
  for (int i = 0; i < 4; ++i)
#pragma unroll
    for (int j = 0; j < 4; ++j)
#pragma unroll
      for (int q = 0; q < 4; ++q) {
        int rr = tm + wr * 64 + i * 16 + fg * 4 + q;
        int cc = tn + wc * 64 + j * 16 + fr;
        Cz[(size_t)rr * N + cc] = acc[i][j][q];
      }
}

// ---------------- old GEMM (pred head only) ----------------
template <int BM, int BN, int WAVES_M, int WAVES_N, int KSPLIT>
__global__ __launch_bounds__(256) void gemm_bt_kernel(
    const unsigned short* __restrict__ A, const unsigned short* __restrict__ Bw,
    float* __restrict__ C, int M, int N, int K) {
  constexpr int BK = 32;
  constexpr int WM = BM / WAVES_M, WN = BN / WAVES_N;
  constexpr int AF = WM / 16, BF = WN / 16;
  constexpr int ASLOT = BM * 4;
  constexpr int BSLOT = BN * 4;
  __shared__ unsigned short As[BM * BK];
  __shared__ unsigned short Bs[BN * BK];

  const int tid = threadIdx.x;
  const int lane = tid & 63, wid = tid >> 6;
  const int wr = wid / WAVES_N, wc = wid % WAVES_N;
  const int tm = blockIdx.x * BM, tn = blockIdx.y * BN;
  const int fr = lane & 15, fg = lane >> 4;

  const int kLen = K / KSPLIT;
  const int kBeg = blockIdx.z * kLen;
  float* Cz = C + (size_t)blockIdx.z * M * N;

  floatx4 acc[AF][BF];
#pragma unroll
  for (int i = 0; i < AF; ++i)
#pragma unroll
    for (int j = 0; j < BF; ++j)
      acc[i][j] = (floatx4){0.f, 0.f, 0.f, 0.f};

  for (int k0 = kBeg; k0 < kBeg + kLen; k0 += BK) {
#pragma unroll
    for (int s = tid; s < ASLOT; s += 256) {
      int row = s >> 2, kb = (s & 3) << 3;
      gload16(&A[(size_t)(tm + row) * K + k0 + kb], &As[s * 8]);
    }
#pragma unroll
    for (int s = tid; s < BSLOT; s += 256) {
      int row = s >> 2, kb = (s & 3) << 3;
      gload16(&Bw[(size_t)(tn + row) * K + k0 + kb], &Bs[s * 8]);
    }
    __syncthreads();

    short8 af[AF], bfv[BF];
#pragma unroll
    for (int i = 0; i < AF; ++i)
      af[i] = *reinterpret_cast<const short8*>(&As[(wr * WM + i * 16 + fr) * BK + fg * 8]);
#pragma unroll
    for (int j = 0; j < BF; ++j)
      bfv[j] = *reinterpret_cast<const short8*>(&Bs[(wc * WN + j * 16 + fr) * BK + fg * 8]);
#pragma unroll
    for (int i = 0; i < AF; ++i)
#pragma unroll
      for (int j = 0; j < BF; ++j)
        acc[i][j] = __builtin_amdgcn_mfma_f32_16x16x32_bf16(af[i], bfv[j], acc[i][j], 0, 0, 0);
    __syncthreads();
  }

#pragma unroll
  for (int i = 0; i < AF; ++i)
#pragma unroll
    for (int j = 0; j < BF; ++j)
#pragma unroll
      for (int q = 0; q < 4; ++q) {
        int rr = tm + wr * WM + i * 16 + fg * 4 + q;
        int cc = tn + wc * WN + j * 16 + fr;
        Cz[(size_t)rr * N + cc] = acc[i][j][q];
      }
}

// ---------------- BatchNorm (train mode) ----------------
__global__ void bn_stats_red_kernel(const float* __restrict__ Yp, float* __restrict__ Yred,
                                    float* __restrict__ psum, float* __restrict__ psq,
                                    int Ncols, int rowsPer, int P, size_t pstride) {
  int c = blockIdx.x * blockDim.x + threadIdx.x;
  int r0 = blockIdx.y * rowsPer;
  float s = 0.f, ss = 0.f;
  for (int r = 0; r < rowsPer; ++r) {
    size_t idx = (size_t)(r0 + r) * Ncols + c;
    float v = Yp[idx];
    for (int p = 1; p < P; ++p) v += Yp[idx + (size_t)p * pstride];
    Yred[idx] = v;
    s += v;
    ss += v * v;
  }
  psum[(size_t)blockIdx.y * Ncols + c] = s;
  psq[(size_t)blockIdx.y * Ncols + c] = ss;
}

__global__ void bn_finalize_kernel(const float* __restrict__ psum, const float* __restrict__ psq,
                                   const float* __restrict__ g, const float* __restrict__ b,
                                   float* __restrict__ scale, float* __restrict__ shift,
                                   int Ncols, int P, float invM) {
  int c = blockIdx.x * blockDim.x + threadIdx.x;
  if (c >= Ncols) return;
  float s = 0.f, ss = 0.f;
  for (int p = 0; p < P; ++p) {
    s += psum[(size_t)p * Ncols + c];
    ss += psq[(size_t)p * Ncols + c];
  }
  float mean = s * invM;
  float var = ss * invM - mean * mean;
  float rstd = rsqrtf(var + 1e-5f);
  float sc = rstd * g[c];
  scale[c] = sc;
  shift[c] = b[c] - mean * sc;
}

__global__ void bn_apply4_kernel(const float4* __restrict__ Y, const float* __restrict__ scale,
                                 const float* __restrict__ shift, ushort4v* __restrict__ X,
                                 int colGroupsMask, int total4) {
  int i = blockIdx.x * blockDim.x + threadIdx.x;
  if (i >= total4) return;
  int c0 = (i & colGroupsMask) * 4;
  float4 v = Y[i];
  ushort4v o;
  o[0] = f2bf(fmaxf(v.x * scale[c0 + 0] + shift[c0 + 0], 0.0f));
  o[1] = f2bf(fmaxf(v.y * scale[c0 + 1] + shift[c0 + 1], 0.0f));
  o[2] = f2bf(fmaxf(v.z * scale[c0 + 2] + shift[c0 + 2], 0.0f));
  o[3] = f2bf(fmaxf(v.w * scale[c0 + 3] + shift[c0 + 3], 0.0f));
  X[i] = o;
}

// ---------------- decode ----------------
__global__ void decode_kernel(const float* __restrict__ Y3, const float* __restrict__ pb,
                              const float* __restrict__ anchors, const int* __restrict__ aid,
                              float* __restrict__ out) {
  int i = blockIdx.x * blockDim.x + threadIdx.x;
  if (i >= 2048 * 94) return;
  int bn = i / 94;
  int ch = i - bn * 94;
  size_t idx = (size_t)bn * 96 + ch;
  float v = Y3[idx] + Y3[idx + 2048 * 96] + Y3[idx + 2 * 2048 * 96] + Y3[idx + 3 * 2048 * 96];
  v += pb[ch];
  float o = v;
  if (ch >= 4 && ch < 22) {
    int q = ch - 4;
    int d = q % 6;   // within-class: 0,1=yx 2,3=lw 4,5=zh
    if (d < 2) {
      float stride_px = (float)(8 << (aid[bn] / 3));
      o = anchors[(size_t)bn * 4 + d] + v * stride_px;
    } else if (d < 4) {
      float cl = fminf(fmaxf(v, -4.0f), 4.0f);
      o = anchors[(size_t)bn * 4 + d] * expf(cl);
    }
  }
  out[i] = o;
}

// ---------------- launch ----------------
extern "C" void kernel_launch(void* const* d_in, const int* in_sizes, int n_in,
                              void* d_out, int out_size, void* d_ws, size_t ws_size,
                              hipStream_t stream) {
  const float* feat_p3   = (const float*)d_in[0];
  const float* feat_p4   = (const float*)d_in[1];
  const float* feat_p5   = (const float*)d_in[2];
  const float* bbox2d    = (const float*)d_in[3];
  const float* anchors   = (const float*)d_in[4];
  const int*   anchor_id = (const int*)d_in[5];
  const float* fc1_w     = (const float*)d_in[6];
  // d_in[7] fc1_b: cancels through train-mode BN (mean subtraction) — unused
  const float* bn1_g     = (const float*)d_in[8];
  const float* bn1_b     = (const float*)d_in[9];
  const float* fc2_w     = (const float*)d_in[10];
  // d_in[11] fc2_b: cancels — unused
  const float* bn2_g     = (const float*)d_in[12];
  const float* bn2_b     = (const float*)d_in[13];
  const float* pred_w    = (const float*)d_in[14];
  const float* pred_b    = (const float*)d_in[15];
  float* out = (float*)d_out;

  const int M = 2048;          // B*N
  const int K1 = 12544;        // 256*7*7
  const int FC = 1024;
  const int RG = 128;          // BN stats row-groups

  char* ws = (char*)d_ws;
  auto alloc = [&](size_t bytes) -> char* {
    char* p = ws;
    ws += (bytes + 255) & ~(size_t)255;
    return p;
  };
  unsigned short* W1b  = (unsigned short*)alloc((size_t)FC * K1 * 2);
  unsigned short* W2b  = (unsigned short*)alloc((size_t)FC * FC * 2);
  unsigned short* W3b  = (unsigned short*)alloc((size_t)96 * FC * 2);
  unsigned short* X1   = (unsigned short*)alloc((size_t)M * K1 * 2);
  float*          Yp   = (float*)alloc((size_t)4 * M * FC * 4);  // split-K partials
  float*          Yr   = (float*)alloc((size_t)M * FC * 4);      // reduced Y
  unsigned short* X2   = (unsigned short*)alloc((size_t)M * FC * 2);
  unsigned short* X3   = (unsigned short*)alloc((size_t)M * FC * 2);
  float*          Y3   = (float*)alloc((size_t)4 * M * 96 * 4);
  float*          ps   = (float*)alloc((size_t)RG * FC * 4);
  float*          pq   = (float*)alloc((size_t)RG * FC * 4);
  float*          sc1  = (float*)alloc((size_t)FC * 4);
  float*          sh1  = (float*)alloc((size_t)FC * 4);
  float*          sc2  = (float*)alloc((size_t)FC * 4);
  float*          sh2  = (float*)alloc((size_t)FC * 4);

  // fused: weight conversions (overlapped) + ROI align -> X1
  prep_roi_kernel<<<GRID_TOTAL, 256, 0, stream>>>(
      feat_p3, feat_p4, feat_p5, bbox2d, anchor_id, X1,
      fc1_w, W1b, fc2_w, W2b, pred_w, W3b);

  // fc1: X1 (2048x12544) @ W1^T -> Yp (4 partials of 2048x1024)
  gemm_bt_swz<4><<<dim3(M / 128, FC / 128, 4), 256, 0, stream>>>(X1, W1b, Yp, M, FC, K1);

  // BN1: reduce partials + stats (512 blocks), finalize, apply+ReLU -> X2 bf16
  bn_stats_red_kernel<<<dim3(FC / 256, RG), 256, 0, stream>>>(Yp, Yr, ps, pq, FC, M / RG, 4, (size_t)M * FC);
  bn_finalize_kernel<<<FC / 256, 256, 0, stream>>>(ps, pq, bn1_g, bn1_b, sc1, sh1, FC, RG, 1.0f / M);
  bn_apply4_kernel<<<(M * FC / 4) / 256, 256, 0, stream>>>(
      (const float4*)Yr, sc1, sh1, (ushort4v*)X2, FC / 4 - 1, M * FC / 4);

  // fc2: X2 @ W2^T -> Yp (2 partials)
  gemm_bt_swz<2><<<dim3(M / 128, FC / 128, 2), 256, 0, stream>>>(X2, W2b, Yp, M, FC, FC);

  // BN2 + ReLU -> X3 bf16
  bn_stats_red_kernel<<<dim3(FC / 256, RG), 256, 0, stream>>>(Yp, Yr, ps, pq, FC, M / RG, 2, (size_t)M * FC);
  bn_finalize_kernel<<<FC / 256, 256, 0, stream>>>(ps, pq, bn2_g, bn2_b, sc2, sh2, FC, RG, 1.0f / M);
  bn_apply4_kernel<<<(M * FC / 4) / 256, 256, 0, stream>>>(
      (const float4*)Yr, sc2, sh2, (ushort4v*)X3, FC / 4 - 1, M * FC / 4);

  // pred head: X3 @ W3p^T -> Y3 (split-K=4 partials of 2048 x 96)
  gemm_bt_kernel<64, 96, 2, 2, 4><<<dim3(M / 64, 1, 4), 256, 0, stream>>>(X3, W3b, Y3, M, 96, FC);

  // decode -> out (2048 x 94)
  decode_kernel<<<(2048 * 94 + 255) / 256, 256, 0, stream>>>(Y3, pred_b, anchors, anchor_id, out);
}